// Round 7
// baseline (158.835 us; speedup 1.0000x reference)
//
#include <hip/hip_runtime.h>
#include <hip/hip_bf16.h>

// RGCN layer, MI355X (gfx950).
// Stage 0: k_wt — pre-transpose weights to bf16 Wt[r][o][k] (one-time, 16 blocks).
// Stage 1: k_gemm — X2[r][n][o] = nf[n] @ W_r. r = in-block loop; nf fragments built
//          once in registers; W fragments loaded DIRECT from global Wt (128KB,
//          L2-resident) — no LDS, no barriers. (R6 post-mortem: LDS staging copy
//          treated short8 as 16 elements -> half of Wl uninitialized -> inf.)
// Stage 2a: per-block-private counting sort of edges into 782 dst-buckets (64 nodes).
// Stage 2b: k_nsort — in-bucket counting sort by exact dst node -> per-node CSR noffs.
// Stage 3: k_ngather — wave-per-node register accumulation + bias + relu. No atomics.
//
// ws: X2 102.4MB | Wt 128KB | rec 8MB | cntT 800KB | offsT 800KB | bsum 3KB | noffs 200KB

#define NN 50000
#define EE 1000000
#define RR 16
#define NBLK 256            // binning blocks
#define EPB 3907            // ceil(EE/NBLK)
#define BSH 6               // 64 nodes per bucket
#define NBUK 782            // ceil(NN/64)
#define NS (NBUK * NBLK)    // 200192 (= 782 scan_a blocks of 256 exactly)
#define SCAP 2048           // k_nsort LDS record capacity (mean 1279, +21 sigma)

typedef __attribute__((ext_vector_type(8))) short short8;
typedef __attribute__((ext_vector_type(4))) float f32x4;

static __device__ inline unsigned short f2bf(float f) {
  union { __hip_bfloat16 h; unsigned short u; } cv;
  cv.h = __float2bfloat16(f);
  return cv.u;
}
static __device__ inline float bf2f(unsigned short u) {
  union { unsigned int i; float f; } cv;
  cv.i = ((unsigned int)u) << 16;
  return cv.f;
}

// ---------------- Stage 0: W[r][k][o] fp32 -> Wt[r][o][k] bf16 ----------------
__global__ __launch_bounds__(256) void k_wt(const float* __restrict__ W,
                                            unsigned short* __restrict__ Wt) {
  __shared__ __align__(16) unsigned short Wl[64][72];
  const int r = blockIdx.x, tid = threadIdx.x;
  for (int i = tid; i < 4096; i += 256) Wl[i & 63][i >> 6] = f2bf(W[(r << 12) + i]);
  __syncthreads();
  // copy-out: thread t -> o = t>>2, 16-element k-chunk at (t&3)*16 (two short8 = 32B)
  const int o = tid >> 2, kc = (tid & 3) << 4;
  const short8 v0 = *reinterpret_cast<const short8*>(&Wl[o][kc]);
  const short8 v1 = *reinterpret_cast<const short8*>(&Wl[o][kc + 8]);
  unsigned short* dst = Wt + (r << 12) + (o << 6) + kc;
  *reinterpret_cast<short8*>(dst) = v0;
  *reinterpret_cast<short8*>(dst + 8) = v1;
}

// ---------------- Stage 1: dense transform, r-inner-loop, W direct from L2 ----------------
// Block: 256 thr / 4 waves, 64 nodes. Wave wv owns nodes base+wv*16+lr.
// A = Wt tile (row = o = c*16 + (lane&15), k = (lane>>4)*8+j)  [global, L2-hot]
// B = nf tile (col = node = lane&15,       k = (lane>>4)*8+j)  [registers, built once]
// D: row = o_local = (lane>>4)*4+reg (4 consecutive o in-lane), col = node = lane&15.
__global__ __launch_bounds__(256) void k_gemm(const float* __restrict__ nf,
                                              const unsigned short* __restrict__ Wt,
                                              unsigned short* __restrict__ X) {
  const int tid = threadIdx.x;
  const int lane = tid & 63, wv = tid >> 6;
  const int lr = lane & 15, lg = lane >> 4;
  const int node = (blockIdx.x << 6) + (wv << 4) + lr;
  short8 bf0, bf1;
  if (node < NN) {
    const float* ap = nf + (size_t)node * 64 + lg * 8;
    float4 v0 = *reinterpret_cast<const float4*>(ap);
    float4 v1 = *reinterpret_cast<const float4*>(ap + 4);
    float4 v2 = *reinterpret_cast<const float4*>(ap + 32);
    float4 v3 = *reinterpret_cast<const float4*>(ap + 36);
    bf0 = short8{(short)f2bf(v0.x), (short)f2bf(v0.y), (short)f2bf(v0.z), (short)f2bf(v0.w),
                 (short)f2bf(v1.x), (short)f2bf(v1.y), (short)f2bf(v1.z), (short)f2bf(v1.w)};
    bf1 = short8{(short)f2bf(v2.x), (short)f2bf(v2.y), (short)f2bf(v2.z), (short)f2bf(v2.w),
                 (short)f2bf(v3.x), (short)f2bf(v3.y), (short)f2bf(v3.z), (short)f2bf(v3.w)};
  } else {
    bf0 = short8{0, 0, 0, 0, 0, 0, 0, 0};
    bf1 = bf0;
  }
  for (int r = 0; r < RR; ++r) {
    #pragma unroll
    for (int c = 0; c < 4; ++c) {
      // A fragment: rows o = c*16 + lr of Wt[r], k-chunks lg*8 and 32+lg*8
      const unsigned short* wp = Wt + (r << 12) + (((c << 4) + lr) << 6) + (lg << 3);
      const short8 a0 = *reinterpret_cast<const short8*>(wp);
      const short8 a1 = *reinterpret_cast<const short8*>(wp + 32);
      f32x4 acc = {0.f, 0.f, 0.f, 0.f};
      acc = __builtin_amdgcn_mfma_f32_16x16x32_bf16(a0, bf0, acc, 0, 0, 0);
      acc = __builtin_amdgcn_mfma_f32_16x16x32_bf16(a1, bf1, acc, 0, 0, 0);
      if (node < NN) {
        uint2 p;
        p.x = (unsigned)f2bf(acc[0]) | ((unsigned)f2bf(acc[1]) << 16);
        p.y = (unsigned)f2bf(acc[2]) | ((unsigned)f2bf(acc[3]) << 16);
        // o = c*16 + lg*4 + {0..3}, row = r*NN + node
        *reinterpret_cast<uint2*>(&X[((size_t)r * NN + node) * 64 + (c << 4) + (lg << 2)]) = p;
      }
    }
  }
}

// ---------------- Stage 2a: per-block-private bucket sort ----------------
__global__ __launch_bounds__(256) void k_hist(const int* __restrict__ edst,
                                              int* __restrict__ cntT) {
  __shared__ int cnt[NBUK];
  const int bl = blockIdx.x, tid = threadIdx.x;
  for (int i = tid; i < NBUK; i += 256) cnt[i] = 0;
  __syncthreads();
  const int e0 = bl * EPB, e1 = min(EE, e0 + EPB);
  for (int e = e0 + tid; e < e1; e += 256) atomicAdd(&cnt[edst[e] >> BSH], 1);
  __syncthreads();
  for (int i = tid; i < NBUK; i += 256) cntT[i * NBLK + bl] = cnt[i];
}

__global__ __launch_bounds__(256) void k_scan_a(const int* __restrict__ cntT,
                                                int* __restrict__ offsT,
                                                int* __restrict__ bsum) {
  __shared__ int s[256];
  const int t = threadIdx.x;
  const int i = blockIdx.x * 256 + t;
  const int v = cntT[i];
  s[t] = v;
  __syncthreads();
  #pragma unroll
  for (int off = 1; off < 256; off <<= 1) {
    const int x = (t >= off) ? s[t - off] : 0;
    __syncthreads();
    s[t] += x;
    __syncthreads();
  }
  offsT[i] = s[t] - v;
  if (t == 255) bsum[blockIdx.x] = s[255];
}

__global__ __launch_bounds__(1024) void k_scan_b(int* __restrict__ bsum) {
  __shared__ int s[1024];
  const int t = threadIdx.x;
  const int v = (t < NBUK) ? bsum[t] : 0;
  s[t] = v;
  __syncthreads();
  #pragma unroll
  for (int off = 1; off < 1024; off <<= 1) {
    const int x = (t >= off) ? s[t - off] : 0;
    __syncthreads();
    s[t] += x;
    __syncthreads();
  }
  if (t < NBUK) bsum[t] = s[t] - v;
}

__global__ __launch_bounds__(256) void k_scan_c(int* __restrict__ offsT,
                                                const int* __restrict__ bsum) {
  const int i = blockIdx.x * 256 + threadIdx.x;
  offsT[i] += bsum[blockIdx.x];
}

__global__ __launch_bounds__(256) void k_scatter(const int* __restrict__ esrc,
                                                 const int* __restrict__ edst,
                                                 const int* __restrict__ etyp,
                                                 const float* __restrict__ enorm,
                                                 const int* __restrict__ offsT,
                                                 uint2* __restrict__ rec) {
  __shared__ int cur[NBUK];
  const int bl = blockIdx.x, tid = threadIdx.x;
  for (int i = tid; i < NBUK; i += 256) cur[i] = offsT[i * NBLK + bl];
  __syncthreads();
  const int e0 = bl * EPB, e1 = min(EE, e0 + EPB);
  for (int e = e0 + tid; e < e1; e += 256) {
    const int d = edst[e];
    const int pos = atomicAdd(&cur[d >> BSH], 1);
    // pack: (typ*NN+src)<<6 | dstlow  (r.x>>6 == X2 row id, typ-major layout)
    rec[pos] = make_uint2(((unsigned)(etyp[e] * NN + esrc[e]) << 6) | (unsigned)(d & 63),
                          __float_as_uint(enorm[e]));
  }
}

// ---------------- Stage 2b: in-bucket sort by exact dst node (in place) ----------------
__global__ __launch_bounds__(256) void k_nsort(const int* __restrict__ offsT,
                                               uint2* __restrict__ rec,
                                               int* __restrict__ noffs) {
  __shared__ uint2 sbuf[SCAP];  // 16 KB
  __shared__ int cnt[64], cur[64];
  const int bu = blockIdx.x, tid = threadIdx.x;
  const int s = offsT[bu * NBLK];
  const int e = (bu == NBUK - 1) ? EE : offsT[(bu + 1) * NBLK];
  const int n = e - s;
  if (tid < 64) cnt[tid] = 0;
  __syncthreads();
  if (n > SCAP) {  // ~impossible overflow: leave unsorted, mark for slow gather
    if (tid < 64) noffs[(bu << BSH) + tid] = -1;
    return;
  }
  for (int i = tid; i < n; i += 256) {
    const uint2 r = rec[s + i];
    sbuf[i] = r;
    atomicAdd(&cnt[r.x & 63u], 1);  // native ds_add_u32
  }
  __syncthreads();
  if (tid < 64) {
    const int v = cnt[tid];
    int x = v;
    #pragma unroll
    for (int off = 1; off < 64; off <<= 1) {
      const int t = __shfl_up(x, off, 64);
      if (tid >= off) x += t;
    }
    cur[tid] = x - v;
    noffs[(bu << BSH) + tid] = s + x - v;
  }
  __syncthreads();
  for (int i = tid; i < n; i += 256) {
    const uint2 r = sbuf[i];
    const int pos = atomicAdd(&cur[r.x & 63u], 1);
    rec[s + pos] = r;
  }
}

// ---------------- Stage 3: wave-per-node register gather + bias + relu ----------------
__global__ __launch_bounds__(256) void k_ngather(const uint2* __restrict__ rec,
                                                 const int* __restrict__ noffs,
                                                 const int* __restrict__ offsT,
                                                 const unsigned short* __restrict__ X,
                                                 const float* __restrict__ bias,
                                                 float* __restrict__ out) {
  const int w = (int)((blockIdx.x * 256 + threadIdx.x) >> 6);  // node id
  const int lane = threadIdx.x & 63;
  if (w >= NN) return;
  const int bu = w >> BSH;
  float a0 = 0.f, a1 = 0.f, a2 = 0.f, a3 = 0.f;
  const int jb = noffs[w];
  if (jb >= 0) {
    const int bend = (bu == NBUK - 1) ? EE : offsT[(bu + 1) * NBLK];
    const int je = ((w & 63) == 63) ? bend : noffs[w + 1];
    int j = jb;
    for (; j + 4 <= je; j += 4) {
      const uint2 r0 = rec[j], r1 = rec[j + 1], r2 = rec[j + 2], r3 = rec[j + 3];
      const float x0 = bf2f(X[(size_t)(r0.x >> 6) * 64 + lane]);
      const float x1 = bf2f(X[(size_t)(r1.x >> 6) * 64 + lane]);
      const float x2 = bf2f(X[(size_t)(r2.x >> 6) * 64 + lane]);
      const float x3 = bf2f(X[(size_t)(r3.x >> 6) * 64 + lane]);
      a0 = fmaf(__uint_as_float(r0.y), x0, a0);
      a1 = fmaf(__uint_as_float(r1.y), x1, a1);
      a2 = fmaf(__uint_as_float(r2.y), x2, a2);
      a3 = fmaf(__uint_as_float(r3.y), x3, a3);
    }
    for (; j < je; ++j) {
      const uint2 r = rec[j];
      a0 = fmaf(__uint_as_float(r.y), bf2f(X[(size_t)(r.x >> 6) * 64 + lane]), a0);
    }
  } else {
    const int s = offsT[bu * NBLK];
    const int e = (bu == NBUK - 1) ? EE : offsT[(bu + 1) * NBLK];
    const unsigned dl = (unsigned)(w & 63);
    for (int j = s; j < e; ++j) {
      const uint2 r = rec[j];
      if ((r.x & 63u) == dl)
        a0 = fmaf(__uint_as_float(r.y), bf2f(X[(size_t)(r.x >> 6) * 64 + lane]), a0);
    }
  }
  const float a = (a0 + a1) + (a2 + a3) + bias[lane];
  out[(size_t)w * 64 + lane] = fmaxf(a, 0.f);
}

extern "C" void kernel_launch(void* const* d_in, const int* in_sizes, int n_in,
                              void* d_out, int out_size, void* d_ws, size_t ws_size,
                              hipStream_t stream) {
  const float* nf = (const float*)d_in[0];
  const int* esrc = (const int*)d_in[1];
  const int* edst = (const int*)d_in[2];
  const int* etyp = (const int*)d_in[3];
  const float* enorm = (const float*)d_in[4];
  const float* W = (const float*)d_in[5];
  const float* bias = (const float*)d_in[6];
  float* out = (float*)d_out;

  char* ws = (char*)d_ws;
  unsigned short* X = (unsigned short*)ws;        // 102,400,000 B
  unsigned short* Wt = (unsigned short*)(ws + 102400000);  // 131,072 B
  uint2* rec = (uint2*)(ws + 102531072);          //   8,000,000 B
  int* cntT = (int*)(ws + 110531072);             //     800,768 B
  int* offsT = (int*)(ws + 111331840);            //     800,768 B
  int* bsum = (int*)(ws + 112132608);             //       3,128 B
  int* noffs = (int*)(ws + 112135736);            //     200,192 B

  k_wt<<<RR, 256, 0, stream>>>(W, Wt);
  k_gemm<<<NBUK, 256, 0, stream>>>(nf, Wt, X);

  k_hist<<<NBLK, 256, 0, stream>>>(edst, cntT);
  k_scan_a<<<NS / 256, 256, 0, stream>>>(cntT, offsT, bsum);
  k_scan_b<<<1, 1024, 0, stream>>>(bsum);
  k_scan_c<<<NS / 256, 256, 0, stream>>>(offsT, bsum);
  k_scatter<<<NBLK, 256, 0, stream>>>(esrc, edst, etyp, enorm, offsT, rec);
  k_nsort<<<NBUK, 256, 0, stream>>>(offsT, rec, noffs);

  k_ngather<<<(NN * 64 + 255) / 256, 256, 0, stream>>>(rec, noffs, offsT, X, bias, out);
}

// Round 8
// 154.495 us; speedup vs baseline: 1.0281x; 1.0281x over previous
//
#include <hip/hip_runtime.h>
#include <hip/hip_bf16.h>

// RGCN layer, MI355X (gfx950).
// Stage 0: k_wt — pre-transpose weights to bf16 Wt[r][o][k] (one-time, 16 blocks).
// Stage 1: k_gemm — X2[r][n][o] = nf[n] @ W_r. Grid (782 node-blocks, 4 r-groups):
//          R7 post-mortem: 782 blocks + serialized L2 loads = 900 cyc/iter latency wall.
//          Now 3128 blocks (TLP) + all-8-fragments-then-8-MFMAs batching (MLP).
// Stage 2a: per-block-private counting sort of edges into 782 dst-buckets (64 nodes).
// Stage 2b: k_nsort — in-bucket counting sort by exact dst node -> per-node CSR noffs.
// Stage 3: k_ngather — wave-per-node register accumulation + bias + relu. No atomics.
//
// ws: X2 102.4MB | Wt 128KB | rec 8MB | cntT 800KB | offsT 800KB | bsum 3KB | noffs 200KB

#define NN 50000
#define EE 1000000
#define RR 16
#define NBLK 256            // binning blocks
#define EPB 3907            // ceil(EE/NBLK)
#define BSH 6               // 64 nodes per bucket
#define NBUK 782            // ceil(NN/64)
#define NS (NBUK * NBLK)    // 200192 (= 782 scan_a blocks of 256 exactly)
#define SCAP 2048           // k_nsort LDS record capacity (mean 1279, +21 sigma)

typedef __attribute__((ext_vector_type(8))) short short8;
typedef __attribute__((ext_vector_type(4))) float f32x4;

static __device__ inline unsigned short f2bf(float f) {
  union { __hip_bfloat16 h; unsigned short u; } cv;
  cv.h = __float2bfloat16(f);
  return cv.u;
}
static __device__ inline float bf2f(unsigned short u) {
  union { unsigned int i; float f; } cv;
  cv.i = ((unsigned int)u) << 16;
  return cv.f;
}

// ---------------- Stage 0: W[r][k][o] fp32 -> Wt[r][o][k] bf16 ----------------
__global__ __launch_bounds__(256) void k_wt(const float* __restrict__ W,
                                            unsigned short* __restrict__ Wt) {
  __shared__ __align__(16) unsigned short Wl[64][72];
  const int r = blockIdx.x, tid = threadIdx.x;
  for (int i = tid; i < 4096; i += 256) Wl[i & 63][i >> 6] = f2bf(W[(r << 12) + i]);
  __syncthreads();
  // copy-out: thread t -> o = t>>2, 16-element k-chunk at (t&3)*16 (two short8 = 32B)
  const int o = tid >> 2, kc = (tid & 3) << 4;
  const short8 v0 = *reinterpret_cast<const short8*>(&Wl[o][kc]);
  const short8 v1 = *reinterpret_cast<const short8*>(&Wl[o][kc + 8]);
  unsigned short* dst = Wt + (r << 12) + (o << 6) + kc;
  *reinterpret_cast<short8*>(dst) = v0;
  *reinterpret_cast<short8*>(dst + 8) = v1;
}

// ---------------- Stage 1: dense transform ----------------
// Grid (NBUK, 4). Block: 256 thr / 4 waves, 64 nodes, relations r0..r0+3.
// A = Wt tile (row = o = c*16 + (lane&15), k = (lane>>4)*8+j)  [global, L2-hot]
// B = nf tile (col = node = lane&15,       k = (lane>>4)*8+j)  [registers, built once]
// D: row = o_local = (lane>>4)*4+reg (4 consecutive o in-lane), col = node = lane&15.
__global__ __launch_bounds__(256) void k_gemm(const float* __restrict__ nf,
                                              const unsigned short* __restrict__ Wt,
                                              unsigned short* __restrict__ X) {
  const int tid = threadIdx.x;
  const int lane = tid & 63, wv = tid >> 6;
  const int lr = lane & 15, lg = lane >> 4;
  const int node = (blockIdx.x << 6) + (wv << 4) + lr;
  const int r0 = blockIdx.y << 2;
  short8 bf0, bf1;
  if (node < NN) {
    const float* ap = nf + (size_t)node * 64 + lg * 8;
    float4 v0 = *reinterpret_cast<const float4*>(ap);
    float4 v1 = *reinterpret_cast<const float4*>(ap + 4);
    float4 v2 = *reinterpret_cast<const float4*>(ap + 32);
    float4 v3 = *reinterpret_cast<const float4*>(ap + 36);
    bf0 = short8{(short)f2bf(v0.x), (short)f2bf(v0.y), (short)f2bf(v0.z), (short)f2bf(v0.w),
                 (short)f2bf(v1.x), (short)f2bf(v1.y), (short)f2bf(v1.z), (short)f2bf(v1.w)};
    bf1 = short8{(short)f2bf(v2.x), (short)f2bf(v2.y), (short)f2bf(v2.z), (short)f2bf(v2.w),
                 (short)f2bf(v3.x), (short)f2bf(v3.y), (short)f2bf(v3.z), (short)f2bf(v3.w)};
  } else {
    bf0 = short8{0, 0, 0, 0, 0, 0, 0, 0};
    bf1 = bf0;
  }
  #pragma unroll
  for (int rr = 0; rr < 4; ++rr) {
    const int r = r0 + rr;
    // batch-load ALL 8 A-fragments (8 independent 16B loads in flight)
    short8 a[8];
    #pragma unroll
    for (int c = 0; c < 4; ++c) {
      const unsigned short* wp = Wt + (r << 12) + (((c << 4) + lr) << 6) + (lg << 3);
      a[2 * c] = *reinterpret_cast<const short8*>(wp);
      a[2 * c + 1] = *reinterpret_cast<const short8*>(wp + 32);
    }
    f32x4 acc[4];
    #pragma unroll
    for (int c = 0; c < 4; ++c) {
      acc[c] = f32x4{0.f, 0.f, 0.f, 0.f};
      acc[c] = __builtin_amdgcn_mfma_f32_16x16x32_bf16(a[2 * c], bf0, acc[c], 0, 0, 0);
      acc[c] = __builtin_amdgcn_mfma_f32_16x16x32_bf16(a[2 * c + 1], bf1, acc[c], 0, 0, 0);
    }
    if (node < NN) {
      #pragma unroll
      for (int c = 0; c < 4; ++c) {
        uint2 p;
        p.x = (unsigned)f2bf(acc[c][0]) | ((unsigned)f2bf(acc[c][1]) << 16);
        p.y = (unsigned)f2bf(acc[c][2]) | ((unsigned)f2bf(acc[c][3]) << 16);
        // o = c*16 + lg*4 + {0..3}, row = r*NN + node
        *reinterpret_cast<uint2*>(&X[((size_t)r * NN + node) * 64 + (c << 4) + (lg << 2)]) = p;
      }
    }
  }
}

// ---------------- Stage 2a: per-block-private bucket sort ----------------
__global__ __launch_bounds__(256) void k_hist(const int* __restrict__ edst,
                                              int* __restrict__ cntT) {
  __shared__ int cnt[NBUK];
  const int bl = blockIdx.x, tid = threadIdx.x;
  for (int i = tid; i < NBUK; i += 256) cnt[i] = 0;
  __syncthreads();
  const int e0 = bl * EPB, e1 = min(EE, e0 + EPB);
  for (int e = e0 + tid; e < e1; e += 256) atomicAdd(&cnt[edst[e] >> BSH], 1);
  __syncthreads();
  for (int i = tid; i < NBUK; i += 256) cntT[i * NBLK + bl] = cnt[i];
}

__global__ __launch_bounds__(256) void k_scan_a(const int* __restrict__ cntT,
                                                int* __restrict__ offsT,
                                                int* __restrict__ bsum) {
  __shared__ int s[256];
  const int t = threadIdx.x;
  const int i = blockIdx.x * 256 + t;
  const int v = cntT[i];
  s[t] = v;
  __syncthreads();
  #pragma unroll
  for (int off = 1; off < 256; off <<= 1) {
    const int x = (t >= off) ? s[t - off] : 0;
    __syncthreads();
    s[t] += x;
    __syncthreads();
  }
  offsT[i] = s[t] - v;
  if (t == 255) bsum[blockIdx.x] = s[255];
}

__global__ __launch_bounds__(1024) void k_scan_b(int* __restrict__ bsum) {
  __shared__ int s[1024];
  const int t = threadIdx.x;
  const int v = (t < NBUK) ? bsum[t] : 0;
  s[t] = v;
  __syncthreads();
  #pragma unroll
  for (int off = 1; off < 1024; off <<= 1) {
    const int x = (t >= off) ? s[t - off] : 0;
    __syncthreads();
    s[t] += x;
    __syncthreads();
  }
  if (t < NBUK) bsum[t] = s[t] - v;
}

__global__ __launch_bounds__(256) void k_scan_c(int* __restrict__ offsT,
                                                const int* __restrict__ bsum) {
  const int i = blockIdx.x * 256 + threadIdx.x;
  offsT[i] += bsum[blockIdx.x];
}

__global__ __launch_bounds__(256) void k_scatter(const int* __restrict__ esrc,
                                                 const int* __restrict__ edst,
                                                 const int* __restrict__ etyp,
                                                 const float* __restrict__ enorm,
                                                 const int* __restrict__ offsT,
                                                 uint2* __restrict__ rec) {
  __shared__ int cur[NBUK];
  const int bl = blockIdx.x, tid = threadIdx.x;
  for (int i = tid; i < NBUK; i += 256) cur[i] = offsT[i * NBLK + bl];
  __syncthreads();
  const int e0 = bl * EPB, e1 = min(EE, e0 + EPB);
  for (int e = e0 + tid; e < e1; e += 256) {
    const int d = edst[e];
    const int pos = atomicAdd(&cur[d >> BSH], 1);
    // pack: (typ*NN+src)<<6 | dstlow  (r.x>>6 == X2 row id, typ-major layout)
    rec[pos] = make_uint2(((unsigned)(etyp[e] * NN + esrc[e]) << 6) | (unsigned)(d & 63),
                          __float_as_uint(enorm[e]));
  }
}

// ---------------- Stage 2b: in-bucket sort by exact dst node (in place) ----------------
__global__ __launch_bounds__(256) void k_nsort(const int* __restrict__ offsT,
                                               uint2* __restrict__ rec,
                                               int* __restrict__ noffs) {
  __shared__ uint2 sbuf[SCAP];  // 16 KB
  __shared__ int cnt[64], cur[64];
  const int bu = blockIdx.x, tid = threadIdx.x;
  const int s = offsT[bu * NBLK];
  const int e = (bu == NBUK - 1) ? EE : offsT[(bu + 1) * NBLK];
  const int n = e - s;
  if (tid < 64) cnt[tid] = 0;
  __syncthreads();
  if (n > SCAP) {  // ~impossible overflow: leave unsorted, mark for slow gather
    if (tid < 64) noffs[(bu << BSH) + tid] = -1;
    return;
  }
  for (int i = tid; i < n; i += 256) {
    const uint2 r = rec[s + i];
    sbuf[i] = r;
    atomicAdd(&cnt[r.x & 63u], 1);  // native ds_add_u32
  }
  __syncthreads();
  if (tid < 64) {
    const int v = cnt[tid];
    int x = v;
    #pragma unroll
    for (int off = 1; off < 64; off <<= 1) {
      const int t = __shfl_up(x, off, 64);
      if (tid >= off) x += t;
    }
    cur[tid] = x - v;
    noffs[(bu << BSH) + tid] = s + x - v;
  }
  __syncthreads();
  for (int i = tid; i < n; i += 256) {
    const uint2 r = sbuf[i];
    const int pos = atomicAdd(&cur[r.x & 63u], 1);
    rec[s + pos] = r;
  }
}

// ---------------- Stage 3: wave-per-node register gather + bias + relu ----------------
__global__ __launch_bounds__(256) void k_ngather(const uint2* __restrict__ rec,
                                                 const int* __restrict__ noffs,
                                                 const int* __restrict__ offsT,
                                                 const unsigned short* __restrict__ X,
                                                 const float* __restrict__ bias,
                                                 float* __restrict__ out) {
  const int w = (int)((blockIdx.x * 256 + threadIdx.x) >> 6);  // node id
  const int lane = threadIdx.x & 63;
  if (w >= NN) return;
  const int bu = w >> BSH;
  float a0 = 0.f, a1 = 0.f, a2 = 0.f, a3 = 0.f;
  const int jb = noffs[w];
  if (jb >= 0) {
    const int bend = (bu == NBUK - 1) ? EE : offsT[(bu + 1) * NBLK];
    const int je = ((w & 63) == 63) ? bend : noffs[w + 1];
    int j = jb;
    for (; j + 4 <= je; j += 4) {
      const uint2 r0 = rec[j], r1 = rec[j + 1], r2 = rec[j + 2], r3 = rec[j + 3];
      const float x0 = bf2f(X[(size_t)(r0.x >> 6) * 64 + lane]);
      const float x1 = bf2f(X[(size_t)(r1.x >> 6) * 64 + lane]);
      const float x2 = bf2f(X[(size_t)(r2.x >> 6) * 64 + lane]);
      const float x3 = bf2f(X[(size_t)(r3.x >> 6) * 64 + lane]);
      a0 = fmaf(__uint_as_float(r0.y), x0, a0);
      a1 = fmaf(__uint_as_float(r1.y), x1, a1);
      a2 = fmaf(__uint_as_float(r2.y), x2, a2);
      a3 = fmaf(__uint_as_float(r3.y), x3, a3);
    }
    for (; j < je; ++j) {
      const uint2 r = rec[j];
      a0 = fmaf(__uint_as_float(r.y), bf2f(X[(size_t)(r.x >> 6) * 64 + lane]), a0);
    }
  } else {
    const int s = offsT[bu * NBLK];
    const int e = (bu == NBUK - 1) ? EE : offsT[(bu + 1) * NBLK];
    const unsigned dl = (unsigned)(w & 63);
    for (int j = s; j < e; ++j) {
      const uint2 r = rec[j];
      if ((r.x & 63u) == dl)
        a0 = fmaf(__uint_as_float(r.y), bf2f(X[(size_t)(r.x >> 6) * 64 + lane]), a0);
    }
  }
  const float a = (a0 + a1) + (a2 + a3) + bias[lane];
  out[(size_t)w * 64 + lane] = fmaxf(a, 0.f);
}

extern "C" void kernel_launch(void* const* d_in, const int* in_sizes, int n_in,
                              void* d_out, int out_size, void* d_ws, size_t ws_size,
                              hipStream_t stream) {
  const float* nf = (const float*)d_in[0];
  const int* esrc = (const int*)d_in[1];
  const int* edst = (const int*)d_in[2];
  const int* etyp = (const int*)d_in[3];
  const float* enorm = (const float*)d_in[4];
  const float* W = (const float*)d_in[5];
  const float* bias = (const float*)d_in[6];
  float* out = (float*)d_out;

  char* ws = (char*)d_ws;
  unsigned short* X = (unsigned short*)ws;        // 102,400,000 B
  unsigned short* Wt = (unsigned short*)(ws + 102400000);  // 131,072 B
  uint2* rec = (uint2*)(ws + 102531072);          //   8,000,000 B
  int* cntT = (int*)(ws + 110531072);             //     800,768 B
  int* offsT = (int*)(ws + 111331840);            //     800,768 B
  int* bsum = (int*)(ws + 112132608);             //       3,128 B
  int* noffs = (int*)(ws + 112135736);            //     200,192 B

  k_wt<<<RR, 256, 0, stream>>>(W, Wt);
  dim3 g1(NBUK, 4);
  k_gemm<<<g1, 256, 0, stream>>>(nf, Wt, X);

  k_hist<<<NBLK, 256, 0, stream>>>(edst, cntT);
  k_scan_a<<<NS / 256, 256, 0, stream>>>(cntT, offsT, bsum);
  k_scan_b<<<1, 1024, 0, stream>>>(bsum);
  k_scan_c<<<NS / 256, 256, 0, stream>>>(offsT, bsum);
  k_scatter<<<NBLK, 256, 0, stream>>>(esrc, edst, etyp, enorm, offsT, rec);
  k_nsort<<<NBUK, 256, 0, stream>>>(offsT, rec, noffs);

  k_ngather<<<(NN * 64 + 255) / 256, 256, 0, stream>>>(rec, noffs, offsT, X, bias, out);
}

// Round 9
// 124.215 us; speedup vs baseline: 1.2787x; 1.2438x over previous
//
#include <hip/hip_runtime.h>
#include <hip/hip_bf16.h>

// RGCN layer, MI355X (gfx950).
// Stage 0: k_wt — pre-transpose weights to bf16 Wt[r][o][k] (one-time, 16 blocks).
// Stage 1: k_gemm — X2[r][n][o] = nf[n] @ W_r. Grid (782, 4), 64 nodes x 4 relations.
//          R8 post-mortem: W direct from L2 keeps VGPR=32 (compiler won't hold 8 frags)
//          -> serialized ~200cyc L2 round-trips. R9 = R8's nf-once registers + R5's
//          PROVEN LDS-resident W (ds_read pipelines at ~50cyc) + packed uint2 stores.
// Stage 2a: per-block-private counting sort of edges into 782 dst-buckets (64 nodes).
// Stage 2b: k_nsort — in-bucket counting sort by exact dst node -> per-node CSR noffs.
// Stage 3: k_ngather — wave-per-node register accumulation + bias + relu. No atomics.
//
// ws: X2 102.4MB | Wt 128KB | rec 8MB | cntT 800KB | offsT 800KB | bsum 3KB | noffs 200KB

#define NN 50000
#define EE 1000000
#define RR 16
#define NBLK 256            // binning blocks
#define EPB 3907            // ceil(EE/NBLK)
#define BSH 6               // 64 nodes per bucket
#define NBUK 782            // ceil(NN/64)
#define NS (NBUK * NBLK)    // 200192 (= 782 scan_a blocks of 256 exactly)
#define SCAP 2048           // k_nsort LDS record capacity (mean 1279, +21 sigma)

typedef __attribute__((ext_vector_type(8))) short short8;
typedef __attribute__((ext_vector_type(4))) float f32x4;

static __device__ inline unsigned short f2bf(float f) {
  union { __hip_bfloat16 h; unsigned short u; } cv;
  cv.h = __float2bfloat16(f);
  return cv.u;
}
static __device__ inline float bf2f(unsigned short u) {
  union { unsigned int i; float f; } cv;
  cv.i = ((unsigned int)u) << 16;
  return cv.f;
}

// ---------------- Stage 0: W[r][k][o] fp32 -> Wt[r][o][k] bf16 ----------------
__global__ __launch_bounds__(256) void k_wt(const float* __restrict__ W,
                                            unsigned short* __restrict__ Wt) {
  __shared__ __align__(16) unsigned short Wl[64][72];
  const int r = blockIdx.x, tid = threadIdx.x;
  for (int i = tid; i < 4096; i += 256) Wl[i & 63][i >> 6] = f2bf(W[(r << 12) + i]);
  __syncthreads();
  // copy-out: thread t -> o = t>>2, 16-element k-chunk at (t&3)*16 (two short8 = 32B)
  const int o = tid >> 2, kc = (tid & 3) << 4;
  const short8 v0 = *reinterpret_cast<const short8*>(&Wl[o][kc]);
  const short8 v1 = *reinterpret_cast<const short8*>(&Wl[o][kc + 8]);
  unsigned short* dst = Wt + (r << 12) + (o << 6) + kc;
  *reinterpret_cast<short8*>(dst) = v0;
  *reinterpret_cast<short8*>(dst + 8) = v1;
}

// ---------------- Stage 1: dense transform ----------------
// Grid (NBUK, 4). Block: 256 thr / 4 waves, 64 nodes, relations r0..r0+3.
// Wl[rr][o][k] staged once from Wt (bf16, 16B copies). Per r: 8 ds_read_b128
// A-fragments + 8 MFMA + 4 packed uint2 stores.
// A = W tile (row = o = c*16 + (lane&15), k = (lane>>4)*8+j)  [LDS]
// B = nf tile (col = node = lane&15,      k = (lane>>4)*8+j)  [registers, built once]
// D: row = o_local = (lane>>4)*4+reg (4 consecutive o in-lane), col = node = lane&15.
__global__ __launch_bounds__(256) void k_gemm(const float* __restrict__ nf,
                                              const unsigned short* __restrict__ Wt,
                                              unsigned short* __restrict__ X) {
  __shared__ __align__(16) unsigned short Wl[4][64][72];  // 36,864 B
  const int tid = threadIdx.x;
  const int lane = tid & 63, wv = tid >> 6;
  const int lr = lane & 15, lg = lane >> 4;
  const int node = (blockIdx.x << 6) + (wv << 4) + lr;
  const int r0 = blockIdx.y << 2;
  // stage 4 relations of Wt into LDS: 32KB, 128B/thread, coalesced 16B loads
  #pragma unroll
  for (int rr = 0; rr < 4; ++rr) {
    const unsigned short* src = Wt + (((size_t)(r0 + rr)) << 12) + (tid << 4);
    const short8 v0 = *reinterpret_cast<const short8*>(src);
    const short8 v1 = *reinterpret_cast<const short8*>(src + 8);
    unsigned short* dst = &Wl[rr][tid >> 2][(tid & 3) << 4];
    *reinterpret_cast<short8*>(dst) = v0;
    *reinterpret_cast<short8*>(dst + 8) = v1;
  }
  short8 bf0, bf1;
  if (node < NN) {
    const float* ap = nf + (size_t)node * 64 + lg * 8;
    float4 v0 = *reinterpret_cast<const float4*>(ap);
    float4 v1 = *reinterpret_cast<const float4*>(ap + 4);
    float4 v2 = *reinterpret_cast<const float4*>(ap + 32);
    float4 v3 = *reinterpret_cast<const float4*>(ap + 36);
    bf0 = short8{(short)f2bf(v0.x), (short)f2bf(v0.y), (short)f2bf(v0.z), (short)f2bf(v0.w),
                 (short)f2bf(v1.x), (short)f2bf(v1.y), (short)f2bf(v1.z), (short)f2bf(v1.w)};
    bf1 = short8{(short)f2bf(v2.x), (short)f2bf(v2.y), (short)f2bf(v2.z), (short)f2bf(v2.w),
                 (short)f2bf(v3.x), (short)f2bf(v3.y), (short)f2bf(v3.z), (short)f2bf(v3.w)};
  } else {
    bf0 = short8{0, 0, 0, 0, 0, 0, 0, 0};
    bf1 = bf0;
  }
  __syncthreads();
  #pragma unroll
  for (int rr = 0; rr < 4; ++rr) {
    const int r = r0 + rr;
    short8 a[8];
    #pragma unroll
    for (int c = 0; c < 4; ++c) {
      a[2 * c] = *reinterpret_cast<const short8*>(&Wl[rr][(c << 4) + lr][lg << 3]);
      a[2 * c + 1] = *reinterpret_cast<const short8*>(&Wl[rr][(c << 4) + lr][32 + (lg << 3)]);
    }
    f32x4 acc[4];
    #pragma unroll
    for (int c = 0; c < 4; ++c) {
      acc[c] = f32x4{0.f, 0.f, 0.f, 0.f};
      acc[c] = __builtin_amdgcn_mfma_f32_16x16x32_bf16(a[2 * c], bf0, acc[c], 0, 0, 0);
      acc[c] = __builtin_amdgcn_mfma_f32_16x16x32_bf16(a[2 * c + 1], bf1, acc[c], 0, 0, 0);
    }
    if (node < NN) {
      #pragma unroll
      for (int c = 0; c < 4; ++c) {
        uint2 p;
        p.x = (unsigned)f2bf(acc[c][0]) | ((unsigned)f2bf(acc[c][1]) << 16);
        p.y = (unsigned)f2bf(acc[c][2]) | ((unsigned)f2bf(acc[c][3]) << 16);
        // o = c*16 + lg*4 + {0..3}, row = r*NN + node
        *reinterpret_cast<uint2*>(&X[((size_t)r * NN + node) * 64 + (c << 4) + (lg << 2)]) = p;
      }
    }
  }
}

// ---------------- Stage 2a: per-block-private bucket sort ----------------
__global__ __launch_bounds__(256) void k_hist(const int* __restrict__ edst,
                                              int* __restrict__ cntT) {
  __shared__ int cnt[NBUK];
  const int bl = blockIdx.x, tid = threadIdx.x;
  for (int i = tid; i < NBUK; i += 256) cnt[i] = 0;
  __syncthreads();
  const int e0 = bl * EPB, e1 = min(EE, e0 + EPB);
  for (int e = e0 + tid; e < e1; e += 256) atomicAdd(&cnt[edst[e] >> BSH], 1);
  __syncthreads();
  for (int i = tid; i < NBUK; i += 256) cntT[i * NBLK + bl] = cnt[i];
}

__global__ __launch_bounds__(256) void k_scan_a(const int* __restrict__ cntT,
                                                int* __restrict__ offsT,
                                                int* __restrict__ bsum) {
  __shared__ int s[256];
  const int t = threadIdx.x;
  const int i = blockIdx.x * 256 + t;
  const int v = cntT[i];
  s[t] = v;
  __syncthreads();
  #pragma unroll
  for (int off = 1; off < 256; off <<= 1) {
    const int x = (t >= off) ? s[t - off] : 0;
    __syncthreads();
    s[t] += x;
    __syncthreads();
  }
  offsT[i] = s[t] - v;
  if (t == 255) bsum[blockIdx.x] = s[255];
}

__global__ __launch_bounds__(1024) void k_scan_b(int* __restrict__ bsum) {
  __shared__ int s[1024];
  const int t = threadIdx.x;
  const int v = (t < NBUK) ? bsum[t] : 0;
  s[t] = v;
  __syncthreads();
  #pragma unroll
  for (int off = 1; off < 1024; off <<= 1) {
    const int x = (t >= off) ? s[t - off] : 0;
    __syncthreads();
    s[t] += x;
    __syncthreads();
  }
  if (t < NBUK) bsum[t] = s[t] - v;
}

__global__ __launch_bounds__(256) void k_scan_c(int* __restrict__ offsT,
                                                const int* __restrict__ bsum) {
  const int i = blockIdx.x * 256 + threadIdx.x;
  offsT[i] += bsum[blockIdx.x];
}

__global__ __launch_bounds__(256) void k_scatter(const int* __restrict__ esrc,
                                                 const int* __restrict__ edst,
                                                 const int* __restrict__ etyp,
                                                 const float* __restrict__ enorm,
                                                 const int* __restrict__ offsT,
                                                 uint2* __restrict__ rec) {
  __shared__ int cur[NBUK];
  const int bl = blockIdx.x, tid = threadIdx.x;
  for (int i = tid; i < NBUK; i += 256) cur[i] = offsT[i * NBLK + bl];
  __syncthreads();
  const int e0 = bl * EPB, e1 = min(EE, e0 + EPB);
  for (int e = e0 + tid; e < e1; e += 256) {
    const int d = edst[e];
    const int pos = atomicAdd(&cur[d >> BSH], 1);
    // pack: (typ*NN+src)<<6 | dstlow  (r.x>>6 == X2 row id, typ-major layout)
    rec[pos] = make_uint2(((unsigned)(etyp[e] * NN + esrc[e]) << 6) | (unsigned)(d & 63),
                          __float_as_uint(enorm[e]));
  }
}

// ---------------- Stage 2b: in-bucket sort by exact dst node (in place) ----------------
__global__ __launch_bounds__(256) void k_nsort(const int* __restrict__ offsT,
                                               uint2* __restrict__ rec,
                                               int* __restrict__ noffs) {
  __shared__ uint2 sbuf[SCAP];  // 16 KB
  __shared__ int cnt[64], cur[64];
  const int bu = blockIdx.x, tid = threadIdx.x;
  const int s = offsT[bu * NBLK];
  const int e = (bu == NBUK - 1) ? EE : offsT[(bu + 1) * NBLK];
  const int n = e - s;
  if (tid < 64) cnt[tid] = 0;
  __syncthreads();
  if (n > SCAP) {  // ~impossible overflow: leave unsorted, mark for slow gather
    if (tid < 64) noffs[(bu << BSH) + tid] = -1;
    return;
  }
  for (int i = tid; i < n; i += 256) {
    const uint2 r = rec[s + i];
    sbuf[i] = r;
    atomicAdd(&cnt[r.x & 63u], 1);  // native ds_add_u32
  }
  __syncthreads();
  if (tid < 64) {
    const int v = cnt[tid];
    int x = v;
    #pragma unroll
    for (int off = 1; off < 64; off <<= 1) {
      const int t = __shfl_up(x, off, 64);
      if (tid >= off) x += t;
    }
    cur[tid] = x - v;
    noffs[(bu << BSH) + tid] = s + x - v;
  }
  __syncthreads();
  for (int i = tid; i < n; i += 256) {
    const uint2 r = sbuf[i];
    const int pos = atomicAdd(&cur[r.x & 63u], 1);
    rec[s + pos] = r;
  }
}

// ---------------- Stage 3: wave-per-node register gather + bias + relu ----------------
__global__ __launch_bounds__(256) void k_ngather(const uint2* __restrict__ rec,
                                                 const int* __restrict__ noffs,
                                                 const int* __restrict__ offsT,
                                                 const unsigned short* __restrict__ X,
                                                 const float* __restrict__ bias,
                                                 float* __restrict__ out) {
  const int w = (int)((blockIdx.x * 256 + threadIdx.x) >> 6);  // node id
  const int lane = threadIdx.x & 63;
  if (w >= NN) return;
  const int bu = w >> BSH;
  float a0 = 0.f, a1 = 0.f, a2 = 0.f, a3 = 0.f;
  const int jb = noffs[w];
  if (jb >= 0) {
    const int bend = (bu == NBUK - 1) ? EE : offsT[(bu + 1) * NBLK];
    const int je = ((w & 63) == 63) ? bend : noffs[w + 1];
    int j = jb;
    for (; j + 4 <= je; j += 4) {
      const uint2 r0 = rec[j], r1 = rec[j + 1], r2 = rec[j + 2], r3 = rec[j + 3];
      const float x0 = bf2f(X[(size_t)(r0.x >> 6) * 64 + lane]);
      const float x1 = bf2f(X[(size_t)(r1.x >> 6) * 64 + lane]);
      const float x2 = bf2f(X[(size_t)(r2.x >> 6) * 64 + lane]);
      const float x3 = bf2f(X[(size_t)(r3.x >> 6) * 64 + lane]);
      a0 = fmaf(__uint_as_float(r0.y), x0, a0);
      a1 = fmaf(__uint_as_float(r1.y), x1, a1);
      a2 = fmaf(__uint_as_float(r2.y), x2, a2);
      a3 = fmaf(__uint_as_float(r3.y), x3, a3);
    }
    for (; j < je; ++j) {
      const uint2 r = rec[j];
      a0 = fmaf(__uint_as_float(r.y), bf2f(X[(size_t)(r.x >> 6) * 64 + lane]), a0);
    }
  } else {
    const int s = offsT[bu * NBLK];
    const int e = (bu == NBUK - 1) ? EE : offsT[(bu + 1) * NBLK];
    const unsigned dl = (unsigned)(w & 63);
    for (int j = s; j < e; ++j) {
      const uint2 r = rec[j];
      if ((r.x & 63u) == dl)
        a0 = fmaf(__uint_as_float(r.y), bf2f(X[(size_t)(r.x >> 6) * 64 + lane]), a0);
    }
  }
  const float a = (a0 + a1) + (a2 + a3) + bias[lane];
  out[(size_t)w * 64 + lane] = fmaxf(a, 0.f);
}

extern "C" void kernel_launch(void* const* d_in, const int* in_sizes, int n_in,
                              void* d_out, int out_size, void* d_ws, size_t ws_size,
                              hipStream_t stream) {
  const float* nf = (const float*)d_in[0];
  const int* esrc = (const int*)d_in[1];
  const int* edst = (const int*)d_in[2];
  const int* etyp = (const int*)d_in[3];
  const float* enorm = (const float*)d_in[4];
  const float* W = (const float*)d_in[5];
  const float* bias = (const float*)d_in[6];
  float* out = (float*)d_out;

  char* ws = (char*)d_ws;
  unsigned short* X = (unsigned short*)ws;        // 102,400,000 B
  unsigned short* Wt = (unsigned short*)(ws + 102400000);  // 131,072 B
  uint2* rec = (uint2*)(ws + 102531072);          //   8,000,000 B
  int* cntT = (int*)(ws + 110531072);             //     800,768 B
  int* offsT = (int*)(ws + 111331840);            //     800,768 B
  int* bsum = (int*)(ws + 112132608);             //       3,128 B
  int* noffs = (int*)(ws + 112135736);            //     200,192 B

  k_wt<<<RR, 256, 0, stream>>>(W, Wt);
  dim3 g1(NBUK, 4);
  k_gemm<<<g1, 256, 0, stream>>>(nf, Wt, X);

  k_hist<<<NBLK, 256, 0, stream>>>(edst, cntT);
  k_scan_a<<<NS / 256, 256, 0, stream>>>(cntT, offsT, bsum);
  k_scan_b<<<1, 1024, 0, stream>>>(bsum);
  k_scan_c<<<NS / 256, 256, 0, stream>>>(offsT, bsum);
  k_scatter<<<NBLK, 256, 0, stream>>>(esrc, edst, etyp, enorm, offsT, rec);
  k_nsort<<<NBUK, 256, 0, stream>>>(offsT, rec, noffs);

  k_ngather<<<(NN * 64 + 255) / 256, 256, 0, stream>>>(rec, noffs, offsT, X, bias, out);
}